// Round 3
// baseline (2564.437 us; speedup 1.0000x reference)
//
#include <hip/hip_runtime.h>
#include <hip/hip_bf16.h>
#include <stdint.h>

// Problem constants (fixed by the reference)
#define B_   4
#define H_   8
#define SQ_  2048
#define SK_  512
#define DM_  4096
#define DK_  512

typedef __bf16 bf16;
typedef __bf16 bf16x8 __attribute__((ext_vector_type(8)));
typedef float  fx4    __attribute__((ext_vector_type(4)));

// ---------------------------------------------------------------------------
// Dtype sniffer. For bf16 tensors, u32 bits[14:7] are the low element's bf16
// exponent field (~always in [100,135] for N(0,1) data). For fp32 tensors the
// same bits are mid-mantissa (uniform, ~14% in-range). 256 samples separate
// the two by >20 sigma. flag=1 -> external tensors are fp32.
__global__ void sniff_dtype(const uint32_t* __restrict__ q, int* __restrict__ flag)
{
    const int l = threadIdx.x;  // 64 lanes
    int cnt = 0;
    #pragma unroll
    for (int i = 0; i < 4; ++i) {
        const uint32_t u = q[l * 4 + i];
        const int e = (u >> 7) & 0xFF;
        cnt += (e >= 100 && e <= 135) ? 1 : 0;
    }
    #pragma unroll
    for (int s = 1; s < 64; s <<= 1) cnt += __shfl_xor(cnt, s);
    if (l == 0) *flag = (cnt < 150) ? 1 : 0;
}

// ---------------------------------------------------------------------------
// C[m,n] = alpha * sum_k A[m,k] * Bt[n,k]  (+ bias[n])
// Core math identical to round 2 (audited). New: `exts` bitmask marks which
// operands are EXTERNAL tensors (bit0 A, bit1 Bt, bit2 bias, bit3 C-store);
// external operands are fp32 when *flagp==1, else bf16. Internal operands are
// always bf16. All leading dims / strides are in ELEMENTS (dtype-agnostic).
__global__ __launch_bounds__(256, 2) void gemm_bt(
    const void* __restrict__ Av, const void* __restrict__ Btv,
    void* __restrict__ Cv, const void* __restrict__ biasv,
    int K, int lda, int ldb, int ldc, float alpha,
    long long sAb, long long sAh, long long sBb, long long sBh,
    long long sCb, long long sCh,
    const int* __restrict__ flagp, int exts)
{
    __shared__ bf16 sA[128 * 64];
    __shared__ bf16 sB[128 * 64];

    const int fl = exts ? *flagp : 0;
    const bool a32 = fl && (exts & 1);
    const bool b32 = fl && (exts & 2);
    const bool bias32 = fl && (exts & 4);
    const bool c32 = fl && (exts & 8);

    const int z = blockIdx.z;
    const int bz = z >> 3, hz = z & 7;
    const size_t offA = (size_t)bz * sAb + (size_t)hz * sAh;
    const size_t offB = (size_t)bz * sBb + (size_t)hz * sBh;
    const size_t offC = (size_t)bz * sCb + (size_t)hz * sCh;

    const int n0 = blockIdx.x * 128;
    const int m0 = blockIdx.y * 128;

    const int t = threadIdx.x;
    const int w = t >> 6, l = t & 63;
    const int lrow = l >> 3, lcol = l & 7;     // staging: 8 lanes x 8 elems cover one 64-col row
    const int wm = (w >> 1) * 64, wn = (w & 1) * 64;
    const int ml = l & 15, quad = l >> 4;      // MFMA fragment lane decomposition

    fx4 acc[4][4];
    const fx4 zero = {0.f, 0.f, 0.f, 0.f};
    #pragma unroll
    for (int i = 0; i < 4; ++i)
        #pragma unroll
        for (int j = 0; j < 4; ++j) acc[i][j] = zero;

    for (int kt = 0; kt < K; kt += 64) {
        // ---- stage A,B 128x64 tiles: 4 rows per wave per tensor ----
        bf16x8 ta[4], tb[4];
        #pragma unroll
        for (int i = 0; i < 4; ++i) {
            const int c = w * 4 + i;            // chunk 0..15
            const int r = c * 8 + lrow;         // tile row 0..127
            const int jj = lcol ^ (r & 7);      // swizzled column-group this lane fetches
            const size_t ea = offA + (size_t)(m0 + r) * lda + kt + jj * 8;
            const size_t eb = offB + (size_t)(n0 + r) * ldb + kt + jj * 8;
            if (a32) {
                const float4* p = (const float4*)((const float*)Av + ea);
                const float4 u0 = p[0], u1 = p[1];
                ta[i][0] = (bf16)u0.x; ta[i][1] = (bf16)u0.y; ta[i][2] = (bf16)u0.z; ta[i][3] = (bf16)u0.w;
                ta[i][4] = (bf16)u1.x; ta[i][5] = (bf16)u1.y; ta[i][6] = (bf16)u1.z; ta[i][7] = (bf16)u1.w;
            } else {
                ta[i] = *(const bf16x8*)((const bf16*)Av + ea);
            }
            if (b32) {
                const float4* p = (const float4*)((const float*)Btv + eb);
                const float4 u0 = p[0], u1 = p[1];
                tb[i][0] = (bf16)u0.x; tb[i][1] = (bf16)u0.y; tb[i][2] = (bf16)u0.z; tb[i][3] = (bf16)u0.w;
                tb[i][4] = (bf16)u1.x; tb[i][5] = (bf16)u1.y; tb[i][6] = (bf16)u1.z; tb[i][7] = (bf16)u1.w;
            } else {
                tb[i] = *(const bf16x8*)((const bf16*)Btv + eb);
            }
        }
        #pragma unroll
        for (int i = 0; i < 4; ++i) {
            const int c = w * 4 + i;
            *(bf16x8*)&sA[c * 512 + l * 8] = ta[i];   // = row r, slot lcol
            *(bf16x8*)&sB[c * 512 + l * 8] = tb[i];
        }
        __syncthreads();

        // ---- compute: 2 k-chunks of 32, 16 MFMAs each ----
        #pragma unroll
        for (int kk = 0; kk < 64; kk += 32) {
            bf16x8 af[4], bfr[4];
            const int jbase = (kk >> 3) + quad;  // column group this lane needs
            #pragma unroll
            for (int mi = 0; mi < 4; ++mi) {
                const int r = wm + mi * 16 + ml;
                af[mi] = *(const bf16x8*)&sA[r * 64 + ((jbase ^ (r & 7)) << 3)];
            }
            #pragma unroll
            for (int ni = 0; ni < 4; ++ni) {
                const int r = wn + ni * 16 + ml;
                bfr[ni] = *(const bf16x8*)&sB[r * 64 + ((jbase ^ (r & 7)) << 3)];
            }
            #pragma unroll
            for (int mi = 0; mi < 4; ++mi)
                #pragma unroll
                for (int ni = 0; ni < 4; ++ni)
                    acc[mi][ni] = __builtin_amdgcn_mfma_f32_16x16x32_bf16(
                        af[mi], bfr[ni], acc[mi][ni], 0, 0, 0);
        }
        __syncthreads();   // all waves done reading before next stage overwrites
    }

    // ---- epilogue: C/D layout col=lane&15, row=(lane>>4)*4+reg ----
    #pragma unroll
    for (int ni = 0; ni < 4; ++ni) {
        const int cg = n0 + wn + ni * 16 + ml;
        const float bv = biasv ? (bias32 ? ((const float*)biasv)[cg] : (float)((const bf16*)biasv)[cg]) : 0.f;
        #pragma unroll
        for (int mi = 0; mi < 4; ++mi) {
            const int rg = m0 + wm + mi * 16 + quad * 4;
            #pragma unroll
            for (int r = 0; r < 4; ++r) {
                const float val = acc[mi][ni][r] * alpha + bv;
                const size_t idx = offC + (size_t)(rg + r) * ldc + cg;
                if (c32) ((float*)Cv)[idx] = val;
                else     ((bf16*)Cv)[idx] = (bf16)val;
            }
        }
    }
}

// In-place row softmax, rows of exactly 512 bf16. One wave per row (8 elems/lane).
// Non-finite inputs are clamped to -1e9 (diagnostic: localizes any NaN origin).
__global__ __launch_bounds__(256) void softmax512(bf16* __restrict__ buf)
{
    const int row = blockIdx.x * 4 + (threadIdx.x >> 6);
    const int l = threadIdx.x & 63;
    bf16* p = buf + (size_t)row * 512 + l * 8;
    bf16x8 v = *(const bf16x8*)p;
    float f[8];
    float mx = -1e30f;
    #pragma unroll
    for (int j = 0; j < 8; ++j) {
        f[j] = (float)v[j];
        if (!(fabsf(f[j]) < 1e30f)) f[j] = -1e9f;   // NaN/Inf guard
        mx = fmaxf(mx, f[j]);
    }
    #pragma unroll
    for (int s = 1; s < 64; s <<= 1) mx = fmaxf(mx, __shfl_xor(mx, s));
    float sum = 0.f;
    #pragma unroll
    for (int j = 0; j < 8; ++j) { f[j] = __expf(f[j] - mx); sum += f[j]; }
    #pragma unroll
    for (int s = 1; s < 64; s <<= 1) sum += __shfl_xor(sum, s);
    const float inv = 1.f / sum;
    #pragma unroll
    for (int j = 0; j < 8; ++j) v[j] = (bf16)(f[j] * inv);
    *(bf16x8*)p = v;
}

// out[z][d][s] = in[b][s][h*512+d], z = b*8+h. 32x32 tiles via LDS. (internal bf16)
__global__ __launch_bounds__(256) void transpose_heads(
    const bf16* __restrict__ in, bf16* __restrict__ out)
{
    __shared__ bf16 tile[32][33];
    const int z = blockIdx.z, b = z >> 3, h = z & 7;
    const int s0 = blockIdx.x * 32, d0 = blockIdx.y * 32;
    const int tx = threadIdx.x, ty = threadIdx.y;   // 32 x 8
    #pragma unroll
    for (int j = 0; j < 4; ++j) {
        const int s = s0 + ty + j * 8;
        tile[ty + j * 8][tx] = in[(size_t)b * SK_ * DM_ + (size_t)s * DM_ + h * DK_ + d0 + tx];
    }
    __syncthreads();
    #pragma unroll
    for (int j = 0; j < 4; ++j) {
        const int d = d0 + ty + j * 8;
        out[(size_t)z * DK_ * SK_ + (size_t)d * SK_ + s0 + tx] = tile[tx][ty + j * 8];
    }
}

extern "C" void kernel_launch(void* const* d_in, const int* in_sizes, int n_in,
                              void* d_out, int out_size, void* d_ws, size_t ws_size,
                              hipStream_t stream)
{
    const void* query = d_in[0];
    const void* key   = d_in[1];
    const void* value = d_in[2];
    const void* imf   = d_in[3];
    const void* W0 = d_in[4];  const void* b0 = d_in[5];
    const void* W1 = d_in[6];  const void* b1 = d_in[7];
    const void* W2 = d_in[8];  const void* b2 = d_in[9];
    const void* W3 = d_in[10]; const void* b3 = d_in[11];
    bf16* ws = (bf16*)d_ws;

    // ws layout (bf16 elems; 8-elem flag header keeps 16B alignment). Total
    // 117,440,528 B (~112 MB). d_out triple-duty: qproj -> s2 -> final out.
    int*  flagp = (int*)d_ws;
    bf16* kproj = ws + 8;                  //  8388608 elems
    bf16* vT    = ws + 8 + 8388608;        //  8388608
    bf16* imfT  = ws + 8 + 16777216;       //  8388608
    bf16* vproj = ws + 8 + 25165824;       //  8388608 (dead after transpose)
    bf16* imfp  = ws + 8 + 33554432;       //  8388608 (dead after transpose)
    bf16* s1    = ws + 8 + 25165824;       // 33554432, overlays vproj+imfp
    bf16* xcat  = s1;                      // overlays s1 (dead after p@imf GEMM)
    bf16* qproj = (bf16*)d_out;            // d_out as scratch until scores GEMM done
    bf16* s2    = (bf16*)d_out;            // d_out again after qproj dies

    const float inv_sqrt_dk = 0.04419417382415922f;  // 1/sqrt(512)

    // 0: decide external dtype (fp32 vs bf16) from query's bit patterns
    sniff_dtype<<<1, 64, 0, stream>>>((const uint32_t*)query, flagp);

    // 1-4: input projections  X @ W^T + b   (external A/B/bias)
    gemm_bt<<<dim3(32, 64, 1), 256, 0, stream>>>(query, W0, qproj, b0, 4096, 4096, 4096, 4096, 1.f, 0,0,0,0,0,0, flagp, 7);
    gemm_bt<<<dim3(32, 16, 1), 256, 0, stream>>>(key,   W1, kproj, b1, 4096, 4096, 4096, 4096, 1.f, 0,0,0,0,0,0, flagp, 7);
    gemm_bt<<<dim3(32, 16, 1), 256, 0, stream>>>(value, W2, vproj, b2, 4096, 4096, 4096, 4096, 1.f, 0,0,0,0,0,0, flagp, 7);
    gemm_bt<<<dim3(32, 16, 1), 256, 0, stream>>>(imf,   W3, imfp,  b3, 4096, 4096, 4096, 4096, 1.f, 0,0,0,0,0,0, flagp, 7);

    // 5: per-head transposes so the @imf and @v einsums become A·B^T
    transpose_heads<<<dim3(16, 16, 32), dim3(32, 8), 0, stream>>>(vproj, vT);
    transpose_heads<<<dim3(16, 16, 32), dim3(32, 8), 0, stream>>>(imfp,  imfT);

    // 6: scores[z][q][k] = q·k / sqrt(dk)    (s1 overlays now-dead vproj/imfp)
    gemm_bt<<<dim3(4, 16, 32), 256, 0, stream>>>(qproj, kproj, s1, nullptr, 512, 4096, 4096, 512, inv_sqrt_dk,
        (long long)SQ_*DM_, (long long)DK_, (long long)SK_*DM_, (long long)DK_,
        (long long)H_*SQ_*SK_, (long long)SQ_*SK_, flagp, 0);
    // 7: p = softmax(scores) in-place
    softmax512<<<dim3(16384), 256, 0, stream>>>(s1);
    // 8: s2[z][q][d] = p @ imf_h   (s2 overwrites now-dead qproj in d_out)
    gemm_bt<<<dim3(4, 16, 32), 256, 0, stream>>>(s1, imfT, s2, nullptr, 512, 512, 512, 512, 1.f,
        (long long)H_*SQ_*SK_, (long long)SQ_*SK_, (long long)H_*DK_*SK_, (long long)DK_*SK_,
        (long long)H_*SQ_*SK_, (long long)SQ_*SK_, flagp, 0);
    // 9: im_attn = softmax(s2) in-place
    softmax512<<<dim3(16384), 256, 0, stream>>>(s2);
    // 10: x[z][q][d] = im_attn @ v_h -> concat-head layout [b][q][h*512+d] (xcat overlays dead s1)
    gemm_bt<<<dim3(4, 16, 32), 256, 0, stream>>>(s2, vT, xcat, nullptr, 512, 512, 512, 4096, 1.f,
        (long long)H_*SQ_*SK_, (long long)SQ_*SK_, (long long)H_*DK_*SK_, (long long)DK_*SK_,
        (long long)SQ_*DM_, (long long)DK_, flagp, 0);
    // 11: out = xcat @ W3^T + b3   (external B/bias; C-store dtype follows flag)
    gemm_bt<<<dim3(32, 64, 1), 256, 0, stream>>>(xcat, W3, d_out, b3, 4096, 4096, 4096, 4096, 1.f, 0,0,0,0,0,0, flagp, 14);
}